// Round 10
// baseline (299.772 us; speedup 1.0000x reference)
//
#include <hip/hip_runtime.h>
#include <hip/hip_bf16.h>

#define BB 2
#define SS 2048
#define HH 2048
#define NHH 16
#define HDD 128

using f32x4  = __attribute__((ext_vector_type(4))) float;
using bf16x8 = __attribute__((ext_vector_type(8))) short;

__device__ __forceinline__ unsigned short f2bf(float x) {
  unsigned int u = __float_as_uint(x);
  unsigned int r = (u + 0x7FFFu + ((u >> 16) & 1u)) >> 16;
  return (unsigned short)r;
}
__device__ __forceinline__ float bf2f(unsigned short u) {
  return __uint_as_float(((unsigned int)u) << 16);
}

__device__ __forceinline__ void gll16(const void* g, void* l) {
  __builtin_amdgcn_global_load_lds(
      (__attribute__((address_space(1))) void*)(g),
      (__attribute__((address_space(3))) void*)(l), 16, 0, 0);
}

#define MFMA16(a, b, c) __builtin_amdgcn_mfma_f32_16x16x32_bf16(a, b, c, 0, 0, 0)

template<int N> __device__ __forceinline__ void wlgkm() {
  static_assert(N == 0 || N == 4 || N == 8, "unsupported lgkmcnt");
  if constexpr (N == 0)      asm volatile("s_waitcnt lgkmcnt(0)" ::: "memory");
  else if constexpr (N == 4) asm volatile("s_waitcnt lgkmcnt(4)" ::: "memory");
  else if constexpr (N == 8) asm volatile("s_waitcnt lgkmcnt(8)" ::: "memory");
}
template<int N> __device__ __forceinline__ void wvm() {
  static_assert(N == 0 || N == 4 || N == 8, "unsupported vmcnt");
  if constexpr (N == 0)      asm volatile("s_waitcnt vmcnt(0)" ::: "memory");
  else if constexpr (N == 4) asm volatile("s_waitcnt vmcnt(4)" ::: "memory");
  else if constexpr (N == 8) asm volatile("s_waitcnt vmcnt(8)" ::: "memory");
}

// ---------------- fused prep: 3 bf16 converts + rope table (1 launch) ----------

__global__ void prep(const float* __restrict__ hs, const float* __restrict__ qkv_w,
                     const float* __restrict__ o_w, unsigned short* __restrict__ hsb,
                     unsigned short* __restrict__ wqkvb, unsigned short* __restrict__ owb,
                     float* __restrict__ tab) {
  int i = blockIdx.x * blockDim.x + threadIdx.x;
  if (i < 6291456) {                       // float4-unit converts
    const float* src; unsigned short* dst; int j;
    if (i < 2097152)      { src = hs;    dst = hsb;   j = i; }
    else if (i < 5242880) { src = qkv_w; dst = wqkvb; j = i - 2097152; }
    else                  { src = o_w;   dst = owb;   j = i - 5242880; }
    float4 v = reinterpret_cast<const float4*>(src)[j];
    ushort4 o;
    o.x = f2bf(v.x); o.y = f2bf(v.y); o.z = f2bf(v.z); o.w = f2bf(v.w);
    reinterpret_cast<ushort4*>(dst)[j] = o;
  } else {                                 // tab: [S][64][2] = cos,sin
    int j = i - 6291456;                   // 0..131071
    int s = j >> 6, jj = j & 63;
    float invf = expf(-logf(10000.f) * ((float)jj / 64.f));
    float a = (float)s * invf;
    tab[j * 2]     = cosf(a);
    tab[j * 2 + 1] = sinf(a);
  }
}

// ---------- QKV GEMM: round-3 pipeline + fused RoPE epilogue (117 us proven) ----

__global__ __launch_bounds__(512, 1)
void gemm_qkv(const unsigned short* __restrict__ A,
              const unsigned short* __restrict__ Bw,
              const float* __restrict__ bias,
              const int* __restrict__ pos,
              const float* __restrict__ tab,
              unsigned short* __restrict__ outQ,
              unsigned short* __restrict__ outK,
              unsigned short* __restrict__ outV,
              int Kdim) {
  __shared__ unsigned short lds_[4][256 * 64];   // lA = slots 0-1, lB = slots 2-3
  const int tid = threadIdx.x;
  const int tn = blockIdx.x, tm = blockIdx.y;
  const int wid = tid >> 6, lane = tid & 63;
  const int wm = wid >> 2, wn = wid & 3;      // 2 x 4 wave grid
  const int lr = lane & 15, lg = lane >> 4;

  const unsigned short* Ab = A + (size_t)tm * 256 * Kdim;
  const unsigned short* Bb = Bw + (size_t)tn * 256 * Kdim;

  f32x4 acc[8][4] = {};
  bf16x8 af[8][2], bfr[4][2];

  const int nt = Kdim >> 6;

  auto stageA = [&](int t, int h) {
    unsigned short* L = lds_[t & 1];
    const int k0 = t << 6;
#pragma unroll
    for (int p = 0; p < 2; ++p) {
      int cl = p * 512 + tid;
      int ri = cl >> 3, c = cl & 7;
      int row = (ri >> 6) * 128 + h * 64 + (ri & 63);
      int cg = c ^ (row & 7);
      gll16(Ab + (size_t)row * Kdim + k0 + (cg << 3), L + row * 64 + (c << 3));
    }
  };
  auto stageB = [&](int t, int h) {
    unsigned short* L = lds_[2 + (t & 1)];
    const int k0 = t << 6;
#pragma unroll
    for (int p = 0; p < 2; ++p) {
      int cl = p * 512 + tid;
      int ri = cl >> 3, c = cl & 7;
      int row = (ri >> 5 << 6) + (h << 5) + (ri & 31);
      int cg = c ^ (row & 7);
      gll16(Bb + (size_t)row * Kdim + k0 + (cg << 3), L + row * 64 + (c << 3));
    }
  };
  auto readAhalf = [&](int g, int h) {
    const unsigned short* la = lds_[g & 1];
#pragma unroll
    for (int mi = h * 4; mi < h * 4 + 4; ++mi) {
      int ra = wm * 128 + mi * 16 + lr;
      af[mi][0] = *reinterpret_cast<const bf16x8*>(la + ra * 64 + ((lg ^ (ra & 7)) << 3));
      af[mi][1] = *reinterpret_cast<const bf16x8*>(la + ra * 64 + (((4 + lg) ^ (ra & 7)) << 3));
    }
  };
  auto readBhalf = [&](int g, int h) {
    const unsigned short* lb = lds_[2 + (g & 1)];
#pragma unroll
    for (int ni = h * 2; ni < h * 2 + 2; ++ni) {
      int rb = wn * 64 + ni * 16 + lr;
      bfr[ni][0] = *reinterpret_cast<const bf16x8*>(lb + rb * 64 + ((lg ^ (rb & 7)) << 3));
      bfr[ni][1] = *reinterpret_cast<const bf16x8*>(lb + rb * 64 + (((4 + lg) ^ (rb & 7)) << 3));
    }
  };
  auto quad = [&](int ah, int bh) {
    __builtin_amdgcn_s_setprio(1);
#pragma unroll
    for (int mi = ah * 4; mi < ah * 4 + 4; ++mi)
#pragma unroll
      for (int ni = bh * 2; ni < bh * 2 + 2; ++ni) {
        acc[mi][ni] = MFMA16(af[mi][0], bfr[ni][0], acc[mi][ni]);
        acc[mi][ni] = MFMA16(af[mi][1], bfr[ni][1], acc[mi][ni]);
      }
    __builtin_amdgcn_s_setprio(0);
  };

  // ---- prologue
  stageA(0, 0); stageA(0, 1); stageB(0, 0); stageB(0, 1);
  stageA(1, 0); stageA(1, 1); stageB(1, 0); stageB(1, 1);
  wvm<8>();
  __builtin_amdgcn_s_barrier();
  __builtin_amdgcn_sched_barrier(0);
  readAhalf(0, 0);
  readBhalf(0, 0);

  for (int g = 0; g < nt; ++g) {
    readBhalf(g, 1);
    wlgkm<4>();
    __builtin_amdgcn_sched_barrier(0);
    quad(0, 0);

    readAhalf(g, 1);
    wlgkm<8>();
    __builtin_amdgcn_sched_barrier(0);
    quad(0, 1);

    asm volatile("s_waitcnt vmcnt(0) lgkmcnt(0)" ::: "memory");
    __builtin_amdgcn_s_barrier();
    __builtin_amdgcn_sched_barrier(0);
    if (g + 1 < nt) readAhalf(g + 1, 0);
    if (g + 2 < nt) { stageA(g + 2, 0); stageA(g + 2, 1); }
    quad(1, 0);

    if (g + 1 < nt) readBhalf(g + 1, 0);
    if (g + 2 < nt) { stageB(g + 2, 0); stageB(g + 2, 1); }
    quad(1, 1);
  }

  // ---------------- epilogue ----------------
  if (tn < 16) {
    // Q/K: stage 256x256 bf16 to LDS (row-XOR swizzle), fused rope, bf16x8 stores.
    unsigned short* Ls = &lds_[0][0];
    __syncthreads();
#pragma unroll
    for (int mi = 0; mi < 8; ++mi) {
#pragma unroll
      for (int ni = 0; ni < 4; ++ni) {
        int n_l = wn * 64 + ni * 16 + lr;
        float bv = bias[tn * 256 + n_l];
#pragma unroll
        for (int r = 0; r < 4; ++r) {
          int m_l = wm * 128 + mi * 16 + lg * 4 + r;
          Ls[m_l * 256 + (n_l ^ ((m_l & 7) << 3))] = f2bf(acc[mi][ni][r] + bv);
        }
      }
    }
    __syncthreads();

    unsigned short* outX = (tn < 8) ? outQ : outK;
    const int jb = (tid & 7) * 8;
    const int r0 = (tid >> 3) * 4;
#pragma unroll
    for (int rr = 0; rr < 4; ++rr) {
      int row = r0 + rr;
      int m = tm * 256 + row;
      int b = m >> 11, s = m & 2047;
      int p = pos[b * 2048 + s];
      float cs[8], sn[8];
#pragma unroll
      for (int j = 0; j < 8; ++j) {
        float2 t2 = *reinterpret_cast<const float2*>(&tab[((size_t)p * 64 + jb + j) * 2]);
        cs[j] = t2.x; sn[j] = t2.y;
      }
      int swz = (row & 7) << 3;
#pragma unroll
      for (int hb = 0; hb < 2; ++hb) {
        bf16x8 x1 = *reinterpret_cast<const bf16x8*>(&Ls[row * 256 + (hb * 128 + (jb ^ swz))]);
        bf16x8 x2 = *reinterpret_cast<const bf16x8*>(&Ls[row * 256 + (hb * 128 + 64 + (jb ^ swz))]);
        bf16x8 y1, y2;
#pragma unroll
        for (int j = 0; j < 8; ++j) {
          float a1 = bf2f((unsigned short)x1[j]);
          float a2 = bf2f((unsigned short)x2[j]);
          y1[j] = (short)f2bf(a1 * cs[j] - a2 * sn[j]);
          y2[j] = (short)f2bf(a2 * cs[j] + a1 * sn[j]);
        }
        int n0 = tn * 256 + hb * 128;
        int h = (n0 >> 7) & 15;
        unsigned short* dst = outX + (((size_t)(b * 16 + h)) * 2048 + s) * 128;
        *reinterpret_cast<bf16x8*>(&dst[jb]) = y1;
        *reinterpret_cast<bf16x8*>(&dst[64 + jb]) = y2;
      }
    }
  } else {
    // V: transposed scalar stores (unchanged).
#pragma unroll
    for (int mi = 0; mi < 8; ++mi) {
#pragma unroll
      for (int ni = 0; ni < 4; ++ni) {
        int n = tn * 256 + wn * 64 + ni * 16 + lr;
        float bv = bias[n];
        int h = (n >> 7) & 15;
        int d = n & 127;
#pragma unroll
        for (int r = 0; r < 4; ++r) {
          int m = tm * 256 + wm * 128 + mi * 16 + lg * 4 + r;
          int b = m >> 11;
          int s = m & 2047;
          outV[(((size_t)(b * 16 + h)) * 128 + d) * 2048 + s] = f2bf(acc[mi][ni][r] + bv);
        }
      }
    }
  }
}

// ---------- 128x128 m97-regime GEMM (O-projection) ----------

template<int MODE>
__global__ __launch_bounds__(256)
void gemm97(const unsigned short* __restrict__ A,
            const unsigned short* __restrict__ Bw,
            float* __restrict__ outF,
            int Kdim) {
  __shared__ unsigned short lA[128 * 64];
  __shared__ unsigned short lB[128 * 64];
  const int tid = threadIdx.x;
  const int tn = blockIdx.x, tm = blockIdx.y;
  const int wid = tid >> 6, lane = tid & 63;
  const int wm = wid >> 1, wn = wid & 1;
  const int lr = lane & 15, lg = lane >> 4;

  const unsigned short* Ab = A + (size_t)tm * 128 * Kdim;
  const unsigned short* Bb = Bw + (size_t)tn * 128 * Kdim;

  f32x4 acc[4][4] = {};

  const unsigned short* sa[4];
  const unsigned short* sb[4];
  unsigned short* da[4];
  unsigned short* db[4];
#pragma unroll
  for (int p = 0; p < 4; ++p) {
    int cl = p * 256 + tid;
    int ri = cl >> 3, c = cl & 7;
    int cg = c ^ (ri & 7);
    sa[p] = Ab + (size_t)ri * Kdim + (cg << 3);
    sb[p] = Bb + (size_t)ri * Kdim + (cg << 3);
    da[p] = lA + ri * 64 + (c << 3);
    db[p] = lB + ri * 64 + (c << 3);
  }

  const int nt = Kdim >> 6;

  for (int k = 0; k < nt; ++k) {
#pragma unroll
    for (int p = 0; p < 4; ++p) {
      gll16(sa[p], da[p]); sa[p] += 64;
      gll16(sb[p], db[p]); sb[p] += 64;
    }
    __syncthreads();

    bf16x8 af[4][2], bf[4][2];
#pragma unroll
    for (int t = 0; t < 4; ++t) {
      int ra = wm * 64 + t * 16 + lr;
      int rb = wn * 64 + t * 16 + lr;
      af[t][0] = *reinterpret_cast<const bf16x8*>(lA + ra * 64 + ((lg ^ (ra & 7)) << 3));
      af[t][1] = *reinterpret_cast<const bf16x8*>(lA + ra * 64 + (((4 + lg) ^ (ra & 7)) << 3));
      bf[t][0] = *reinterpret_cast<const bf16x8*>(lB + rb * 64 + ((lg ^ (rb & 7)) << 3));
      bf[t][1] = *reinterpret_cast<const bf16x8*>(lB + rb * 64 + (((4 + lg) ^ (rb & 7)) << 3));
    }
#pragma unroll
    for (int i = 0; i < 4; ++i)
#pragma unroll
      for (int j = 0; j < 4; ++j) {
        acc[i][j] = MFMA16(af[i][0], bf[j][0], acc[i][j]);
        acc[i][j] = MFMA16(af[i][1], bf[j][1], acc[i][j]);
      }
    __syncthreads();
  }

#pragma unroll
  for (int i = 0; i < 4; ++i) {
#pragma unroll
    for (int j = 0; j < 4; ++j) {
      int n = tn * 128 + wn * 64 + j * 16 + lr;
#pragma unroll
      for (int r = 0; r < 4; ++r) {
        int m = tm * 128 + wm * 64 + i * 16 + lg * 4 + r;
        outF[(size_t)m * 2048 + n] = acc[i][j][r];
      }
    }
  }
}

// ---------------- flash attention: QBLK=128, 8 waves, work-balanced ----------------
// Block bx handles q-tiles {15-bx, bx} (128 rows each): exactly 34 kv-iters.
// K/V double-buffered; stage(kt+1) before compute(kt); counted vmcnt(4)
// (4 loads/thread/stage at 512 thr); raw s_barrier; T13 defer-max; exp2 domain.
// vs r9: staging bytes per FLOP halved, waves/SIMD 2 -> 4 (80 KB LDS,
// 2 blocks/CU), VGPR trimmed + capped 128 via __launch_bounds__(512,4).

__global__ __launch_bounds__(512, 4)
void attn_fwd(const unsigned short* __restrict__ Qr,
              const unsigned short* __restrict__ Kr,
              const unsigned short* __restrict__ Vt,
              unsigned short* __restrict__ attnb) {
  __shared__ unsigned short Ks[2][64 * 128];   // 32 KB
  __shared__ unsigned short Vs[2][128 * 64];   // 32 KB
  __shared__ unsigned short Ps[128 * 64];      // 16 KB
  const int bx = blockIdx.x, bh = blockIdx.y;
  const int tid = threadIdx.x;
  const int wid = tid >> 6, lane = tid & 63;   // wid 0..7 -> q-rows wid*16..
  const int lr = lane & 15, lg = lane >> 4;
  const unsigned short* Qb = Qr + (size_t)bh * SS * HDD;
  const unsigned short* Kb = Kr + (size_t)bh * SS * HDD;
  const unsigned short* Vb = Vt + (size_t)bh * HDD * SS;
  const int b = bh >> 4, h = bh & 15;
  const float SC2 = 0.12751763f;               // 1/sqrt(128) * log2(e)

#pragma unroll 1
  for (int qi = 0; qi < 2; ++qi) {
    const int qt = qi ? bx : (15 - bx);        // q-tile of 128 rows
    const int nkt = 2 * qt + 2;                // kv-tiles of 64

    const unsigned short* ksrc[2];
    const unsigned short* vsrc[2];
    int dst8[2];
#pragma unroll
    for (int ch = 0; ch < 2; ++ch) {
      int c = tid + ch * 512;                  // 0..1023 chunks
      int kr = c >> 4, kc = c & 15;
      ksrc[ch] = Kb + (size_t)kr * 128 + ((kc ^ (kr & 7)) << 3);
      int vr = c >> 3, vc = c & 7;
      vsrc[ch] = Vb + (size_t)vr * SS + ((vc ^ (vr & 7)) << 3);
      dst8[ch] = c * 8;
    }

    bf16x8 qf[4];
#pragma unroll
    for (int kk = 0; kk < 4; ++kk)
      qf[kk] = *reinterpret_cast<const bf16x8*>(
          Qb + ((size_t)(qt * 128 + wid * 16 + lr)) * 128 + kk * 32 + lg * 8);

    f32x4 oacc[8] = {};
    float mrow[4], lsum[4];
#pragma unroll
    for (int r = 0; r < 4; ++r) { mrow[r] = -1e30f; lsum[r] = 0.f; }

    int cur = 0;
    // stage kv-tile 0 into buf 0
#pragma unroll
    for (int ch = 0; ch < 2; ++ch) {
      gll16(ksrc[ch], Ks[0] + dst8[ch]); ksrc[ch] += 64 * 128;
      gll16(vsrc[ch], Vs[0] + dst8[ch]); vsrc[ch] += 64;
    }

#pragma unroll 1
    for (int kt = 0; kt < nkt; ++kt) {
      if (kt + 1 < nkt) {
#pragma unroll
        for (int ch = 0; ch < 2; ++ch) {
          gll16(ksrc[ch], Ks[cur ^ 1] + dst8[ch]); ksrc[ch] += 64 * 128;
          gll16(vsrc[ch], Vs[cur ^ 1] + dst8[ch]); vsrc[ch] += 64;
        }
        wvm<4>();                              // retire stage(kt)
      } else {
        wvm<0>();
      }
      __builtin_amdgcn_s_barrier();
      __builtin_amdgcn_sched_barrier(0);

      float sv[4][4];
#pragma unroll
      for (int nt = 0; nt < 4; ++nt) {
        f32x4 sa = {};
#pragma unroll
        for (int kk = 0; kk < 4; ++kk) {
          int row = nt * 16 + lr;
          bf16x8 kf = *reinterpret_cast<const bf16x8*>(
              Ks[cur] + row * 128 + (((kk * 4 + lg) ^ (row & 7)) << 3));
          sa = __builtin_amdgcn_mfma_f32_16x16x32_bf16(qf[kk], kf, sa, 0, 0, 0);
        }
#pragma unroll
        for (int r = 0; r < 4; ++r) {
          float s = sa[r] * SC2;
          // mask only possible when kt>>1 == qt; kv offset within = (kt&1)*64
          if ((kt >> 1) == qt &&
              ((kt & 1) << 6) + nt * 16 + lr > wid * 16 + lg * 4 + r) s -= 1.5e9f;
          sv[nt][r] = s;
        }
      }

      float tmax[4];
#pragma unroll
      for (int r = 0; r < 4; ++r)
        tmax[r] = fmaxf(fmaxf(sv[0][r], sv[1][r]), fmaxf(sv[2][r], sv[3][r]));
#pragma unroll
      for (int r = 0; r < 4; ++r) {
        tmax[r] = fmaxf(tmax[r], __shfl_xor(tmax[r], 1));
        tmax[r] = fmaxf(tmax[r], __shfl_xor(tmax[r], 2));
        tmax[r] = fmaxf(tmax[r], __shfl_xor(tmax[r], 4));
        tmax[r] = fmaxf(tmax[r], __shfl_xor(tmax[r], 8));
      }

      float need = fmaxf(fmaxf(tmax[0] - mrow[0], tmax[1] - mrow[1]),
                         fmaxf(tmax[2] - mrow[2], tmax[3] - mrow[3]));
      if (__any(need > 11.54f)) {
#pragma unroll
        for (int r = 0; r < 4; ++r) {
          float mn = fmaxf(mrow[r], tmax[r]);
          float fr = exp2f(mrow[r] - mn);
          mrow[r] = mn;
          lsum[r] *= fr;
#pragma unroll
          for (int ct = 0; ct < 8; ++ct) oacc[ct][r] *= fr;
        }
      }

      float tsum[4] = {0.f, 0.f, 0.f, 0.f};
#pragma unroll
      for (int nt = 0; nt < 4; ++nt) {
        int colc = nt * 2 + (lr >> 3);
#pragma unroll
        for (int r = 0; r < 4; ++r) {
          float p = exp2f(sv[nt][r] - mrow[r]);
          tsum[r] += p;
          int row = wid * 16 + lg * 4 + r;    // 0..127
          Ps[row * 64 + ((colc ^ (row & 7)) << 3) + (lr & 7)] = f2bf(p);
        }
      }
#pragma unroll
      for (int r = 0; r < 4; ++r) {
        tsum[r] += __shfl_xor(tsum[r], 1);
        tsum[r] += __shfl_xor(tsum[r], 2);
        tsum[r] += __shfl_xor(tsum[r], 4);
        tsum[r] += __shfl_xor(tsum[r], 8);
        lsum[r] += tsum[r];
      }

      bf16x8 pf[2];
#pragma unroll
      for (int ks = 0; ks < 2; ++ks) {
        int row = wid * 16 + lr;
        pf[ks] = *reinterpret_cast<const bf16x8*>(
            Ps + row * 64 + (((ks * 4 + lg) ^ (row & 7)) << 3));
      }
#pragma unroll
      for (int ct = 0; ct < 8; ++ct) {
#pragma unroll
        for (int ks = 0; ks < 2; ++ks) {
          int row = ct * 16 + lr;
          bf16x8 vf = *reinterpret_cast<const bf16x8*>(
              Vs[cur] + row * 64 + (((ks * 4 + lg) ^ (row & 7)) << 3));
          oacc[ct] = __builtin_amdgcn_mfma_f32_16x16x32_bf16(pf[ks], vf, oacc[ct], 0, 0, 0);
        }
      }
      __builtin_amdgcn_s_barrier();            // readers of buf 'cur' done
      cur ^= 1;
    }

#pragma unroll
    for (int r = 0; r < 4; ++r) {
      float rl = 1.f / lsum[r];
      int qg = qt * 128 + wid * 16 + lg * 4 + r;
#pragma unroll
      for (int ct = 0; ct < 8; ++ct) {
        int d = ct * 16 + lr;
        attnb[((size_t)b * SS + qg) * HH + h * 128 + d] = f2bf(oacc[ct][r] * rl);
      }
    }
  }
}

// ---------------- launch ----------------

extern "C" void kernel_launch(void* const* d_in, const int* in_sizes, int n_in,
                              void* d_out, int out_size, void* d_ws, size_t ws_size,
                              hipStream_t stream) {
  const float* hs     = (const float*)d_in[0];
  const int*   pos    = (const int*)d_in[1];
  const float* qkv_w  = (const float*)d_in[3];
  const float* qkv_b  = (const float*)d_in[4];
  const float* o_w    = (const float*)d_in[5];
  float* out = (float*)d_out;
  char* ws = (char*)d_ws;

  unsigned short* hsb   = (unsigned short*)(ws);                  // 16 MB
  unsigned short* wqkvb = (unsigned short*)(ws + 16777216);       // 24 MB
  unsigned short* owb   = (unsigned short*)(ws + 41943040);       // 8 MB
  unsigned short* Qr    = (unsigned short*)(ws + 50331648);       // 16 MB
  unsigned short* Kr    = (unsigned short*)(ws + 67108864);       // 16 MB
  unsigned short* Vt    = (unsigned short*)(ws + 83886080);       // 16 MB
  unsigned short* attnb = (unsigned short*)(ws + 100663296);      // 16 MB
  float*          tab   = (float*)(ws + 117440512);               // 1 MB

  // fused converts + rope table: (6291456 + 131072) / 256 = 25088 blocks
  prep<<<25088, 256, 0, stream>>>(hs, qkv_w, o_w, hsb, wqkvb, owb, tab);

  // QKV + fused RoPE: grid 24x16 = 384 blocks.
  gemm_qkv<<<dim3(24, 16), 512, 0, stream>>>(hsb, wqkvb, qkv_b, pos, tab, Qr, Kr, Vt, 2048);
  // attention: QBLK=128, grid 8x32 = 256 blocks, 512 threads.
  attn_fwd<<<dim3(8, 32), 512, 0, stream>>>(Qr, Kr, Vt, attnb);
  // O-proj: 128x128 m97-regime, grid 16x32 = 512 blocks.
  gemm97<0><<<dim3(16, 32), 256, 0, stream>>>(attnb, owb, out, 2048);
}

// Round 11
// 273.385 us; speedup vs baseline: 1.0965x; 1.0965x over previous
//
#include <hip/hip_runtime.h>
#include <hip/hip_bf16.h>

#define BB 2
#define SS 2048
#define HH 2048
#define NHH 16
#define HDD 128

using f32x4  = __attribute__((ext_vector_type(4))) float;
using bf16x8 = __attribute__((ext_vector_type(8))) short;

__device__ __forceinline__ unsigned short f2bf(float x) {
  unsigned int u = __float_as_uint(x);
  unsigned int r = (u + 0x7FFFu + ((u >> 16) & 1u)) >> 16;
  return (unsigned short)r;
}
__device__ __forceinline__ float bf2f(unsigned short u) {
  return __uint_as_float(((unsigned int)u) << 16);
}

__device__ __forceinline__ void gll16(const void* g, void* l) {
  __builtin_amdgcn_global_load_lds(
      (__attribute__((address_space(1))) void*)(g),
      (__attribute__((address_space(3))) void*)(l), 16, 0, 0);
}

#define MFMA16(a, b, c) __builtin_amdgcn_mfma_f32_16x16x32_bf16(a, b, c, 0, 0, 0)

template<int N> __device__ __forceinline__ void wlgkm() {
  static_assert(N == 0 || N == 4 || N == 8, "unsupported lgkmcnt");
  if constexpr (N == 0)      asm volatile("s_waitcnt lgkmcnt(0)" ::: "memory");
  else if constexpr (N == 4) asm volatile("s_waitcnt lgkmcnt(4)" ::: "memory");
  else if constexpr (N == 8) asm volatile("s_waitcnt lgkmcnt(8)" ::: "memory");
}
template<int N> __device__ __forceinline__ void wvm() {
  static_assert(N == 0 || N == 8, "unsupported vmcnt");
  if constexpr (N == 0)      asm volatile("s_waitcnt vmcnt(0)" ::: "memory");
  else if constexpr (N == 8) asm volatile("s_waitcnt vmcnt(8)" ::: "memory");
}

// ---------------- fused prep: 3 bf16 converts + rope table (1 launch) ----------

__global__ void prep(const float* __restrict__ hs, const float* __restrict__ qkv_w,
                     const float* __restrict__ o_w, unsigned short* __restrict__ hsb,
                     unsigned short* __restrict__ wqkvb, unsigned short* __restrict__ owb,
                     float* __restrict__ tab) {
  int i = blockIdx.x * blockDim.x + threadIdx.x;
  if (i < 6291456) {                       // float4-unit converts
    const float* src; unsigned short* dst; int j;
    if (i < 2097152)      { src = hs;    dst = hsb;   j = i; }
    else if (i < 5242880) { src = qkv_w; dst = wqkvb; j = i - 2097152; }
    else                  { src = o_w;   dst = owb;   j = i - 5242880; }
    float4 v = reinterpret_cast<const float4*>(src)[j];
    ushort4 o;
    o.x = f2bf(v.x); o.y = f2bf(v.y); o.z = f2bf(v.z); o.w = f2bf(v.w);
    reinterpret_cast<ushort4*>(dst)[j] = o;
  } else {                                 // tab: [S][64][2] = cos,sin
    int j = i - 6291456;                   // 0..131071
    int s = j >> 6, jj = j & 63;
    float invf = expf(-logf(10000.f) * ((float)jj / 64.f));
    float a = (float)s * invf;
    tab[j * 2]     = cosf(a);
    tab[j * 2 + 1] = sinf(a);
  }
}

// ---------- QKV GEMM: round-3 pipeline + fused RoPE epilogue (117 us proven) ----

__global__ __launch_bounds__(512, 1)
void gemm_qkv(const unsigned short* __restrict__ A,
              const unsigned short* __restrict__ Bw,
              const float* __restrict__ bias,
              const int* __restrict__ pos,
              const float* __restrict__ tab,
              unsigned short* __restrict__ outQ,
              unsigned short* __restrict__ outK,
              unsigned short* __restrict__ outV,
              int Kdim) {
  __shared__ unsigned short lds_[4][256 * 64];   // lA = slots 0-1, lB = slots 2-3
  const int tid = threadIdx.x;
  const int tn = blockIdx.x, tm = blockIdx.y;
  const int wid = tid >> 6, lane = tid & 63;
  const int wm = wid >> 2, wn = wid & 3;      // 2 x 4 wave grid
  const int lr = lane & 15, lg = lane >> 4;

  const unsigned short* Ab = A + (size_t)tm * 256 * Kdim;
  const unsigned short* Bb = Bw + (size_t)tn * 256 * Kdim;

  f32x4 acc[8][4] = {};
  bf16x8 af[8][2], bfr[4][2];

  const int nt = Kdim >> 6;

  auto stageA = [&](int t, int h) {
    unsigned short* L = lds_[t & 1];
    const int k0 = t << 6;
#pragma unroll
    for (int p = 0; p < 2; ++p) {
      int cl = p * 512 + tid;
      int ri = cl >> 3, c = cl & 7;
      int row = (ri >> 6) * 128 + h * 64 + (ri & 63);
      int cg = c ^ (row & 7);
      gll16(Ab + (size_t)row * Kdim + k0 + (cg << 3), L + row * 64 + (c << 3));
    }
  };
  auto stageB = [&](int t, int h) {
    unsigned short* L = lds_[2 + (t & 1)];
    const int k0 = t << 6;
#pragma unroll
    for (int p = 0; p < 2; ++p) {
      int cl = p * 512 + tid;
      int ri = cl >> 3, c = cl & 7;
      int row = (ri >> 5 << 6) + (h << 5) + (ri & 31);
      int cg = c ^ (row & 7);
      gll16(Bb + (size_t)row * Kdim + k0 + (cg << 3), L + row * 64 + (c << 3));
    }
  };
  auto readAhalf = [&](int g, int h) {
    const unsigned short* la = lds_[g & 1];
#pragma unroll
    for (int mi = h * 4; mi < h * 4 + 4; ++mi) {
      int ra = wm * 128 + mi * 16 + lr;
      af[mi][0] = *reinterpret_cast<const bf16x8*>(la + ra * 64 + ((lg ^ (ra & 7)) << 3));
      af[mi][1] = *reinterpret_cast<const bf16x8*>(la + ra * 64 + (((4 + lg) ^ (ra & 7)) << 3));
    }
  };
  auto readBhalf = [&](int g, int h) {
    const unsigned short* lb = lds_[2 + (g & 1)];
#pragma unroll
    for (int ni = h * 2; ni < h * 2 + 2; ++ni) {
      int rb = wn * 64 + ni * 16 + lr;
      bfr[ni][0] = *reinterpret_cast<const bf16x8*>(lb + rb * 64 + ((lg ^ (rb & 7)) << 3));
      bfr[ni][1] = *reinterpret_cast<const bf16x8*>(lb + rb * 64 + (((4 + lg) ^ (rb & 7)) << 3));
    }
  };
  auto quad = [&](int ah, int bh) {
    __builtin_amdgcn_s_setprio(1);
#pragma unroll
    for (int mi = ah * 4; mi < ah * 4 + 4; ++mi)
#pragma unroll
      for (int ni = bh * 2; ni < bh * 2 + 2; ++ni) {
        acc[mi][ni] = MFMA16(af[mi][0], bfr[ni][0], acc[mi][ni]);
        acc[mi][ni] = MFMA16(af[mi][1], bfr[ni][1], acc[mi][ni]);
      }
    __builtin_amdgcn_s_setprio(0);
  };

  // ---- prologue
  stageA(0, 0); stageA(0, 1); stageB(0, 0); stageB(0, 1);
  stageA(1, 0); stageA(1, 1); stageB(1, 0); stageB(1, 1);
  wvm<8>();
  __builtin_amdgcn_s_barrier();
  __builtin_amdgcn_sched_barrier(0);
  readAhalf(0, 0);
  readBhalf(0, 0);

  for (int g = 0; g < nt; ++g) {
    readBhalf(g, 1);
    wlgkm<4>();
    __builtin_amdgcn_sched_barrier(0);
    quad(0, 0);

    readAhalf(g, 1);
    wlgkm<8>();
    __builtin_amdgcn_sched_barrier(0);
    quad(0, 1);

    asm volatile("s_waitcnt vmcnt(0) lgkmcnt(0)" ::: "memory");
    __builtin_amdgcn_s_barrier();
    __builtin_amdgcn_sched_barrier(0);
    if (g + 1 < nt) readAhalf(g + 1, 0);
    if (g + 2 < nt) { stageA(g + 2, 0); stageA(g + 2, 1); }
    quad(1, 0);

    if (g + 1 < nt) readBhalf(g + 1, 0);
    if (g + 2 < nt) { stageB(g + 2, 0); stageB(g + 2, 1); }
    quad(1, 1);
  }

  // ---------------- epilogue ----------------
  if (tn < 16) {
    // Q/K: stage 256x256 bf16 to LDS (row-XOR swizzle), fused rope, bf16x8 stores.
    unsigned short* Ls = &lds_[0][0];
    __syncthreads();
#pragma unroll
    for (int mi = 0; mi < 8; ++mi) {
#pragma unroll
      for (int ni = 0; ni < 4; ++ni) {
        int n_l = wn * 64 + ni * 16 + lr;
        float bv = bias[tn * 256 + n_l];
#pragma unroll
        for (int r = 0; r < 4; ++r) {
          int m_l = wm * 128 + mi * 16 + lg * 4 + r;
          Ls[m_l * 256 + (n_l ^ ((m_l & 7) << 3))] = f2bf(acc[mi][ni][r] + bv);
        }
      }
    }
    __syncthreads();

    unsigned short* outX = (tn < 8) ? outQ : outK;
    const int jb = (tid & 7) * 8;
    const int r0 = (tid >> 3) * 4;
#pragma unroll
    for (int rr = 0; rr < 4; ++rr) {
      int row = r0 + rr;
      int m = tm * 256 + row;
      int b = m >> 11, s = m & 2047;
      int p = pos[b * 2048 + s];
      float cs[8], sn[8];
#pragma unroll
      for (int j = 0; j < 8; ++j) {
        float2 t2 = *reinterpret_cast<const float2*>(&tab[((size_t)p * 64 + jb + j) * 2]);
        cs[j] = t2.x; sn[j] = t2.y;
      }
      int swz = (row & 7) << 3;
#pragma unroll
      for (int hb = 0; hb < 2; ++hb) {
        bf16x8 x1 = *reinterpret_cast<const bf16x8*>(&Ls[row * 256 + (hb * 128 + (jb ^ swz))]);
        bf16x8 x2 = *reinterpret_cast<const bf16x8*>(&Ls[row * 256 + (hb * 128 + 64 + (jb ^ swz))]);
        bf16x8 y1, y2;
#pragma unroll
        for (int j = 0; j < 8; ++j) {
          float a1 = bf2f((unsigned short)x1[j]);
          float a2 = bf2f((unsigned short)x2[j]);
          y1[j] = (short)f2bf(a1 * cs[j] - a2 * sn[j]);
          y2[j] = (short)f2bf(a2 * cs[j] + a1 * sn[j]);
        }
        int n0 = tn * 256 + hb * 128;
        int h = (n0 >> 7) & 15;
        unsigned short* dst = outX + (((size_t)(b * 16 + h)) * 2048 + s) * 128;
        *reinterpret_cast<bf16x8*>(&dst[jb]) = y1;
        *reinterpret_cast<bf16x8*>(&dst[64 + jb]) = y2;
      }
    }
  } else {
    // V: transposed scalar stores (unchanged).
#pragma unroll
    for (int mi = 0; mi < 8; ++mi) {
#pragma unroll
      for (int ni = 0; ni < 4; ++ni) {
        int n = tn * 256 + wn * 64 + ni * 16 + lr;
        float bv = bias[n];
        int h = (n >> 7) & 15;
        int d = n & 127;
#pragma unroll
        for (int r = 0; r < 4; ++r) {
          int m = tm * 256 + wm * 128 + mi * 16 + lg * 4 + r;
          int b = m >> 11;
          int s = m & 2047;
          outV[(((size_t)(b * 16 + h)) * 128 + d) * 2048 + s] = f2bf(acc[mi][ni][r] + bv);
        }
      }
    }
  }
}

// ---------- 128x128 m97-regime GEMM (O-projection) ----------

template<int MODE>
__global__ __launch_bounds__(256)
void gemm97(const unsigned short* __restrict__ A,
            const unsigned short* __restrict__ Bw,
            float* __restrict__ outF,
            int Kdim) {
  __shared__ unsigned short lA[128 * 64];
  __shared__ unsigned short lB[128 * 64];
  const int tid = threadIdx.x;
  const int tn = blockIdx.x, tm = blockIdx.y;
  const int wid = tid >> 6, lane = tid & 63;
  const int wm = wid >> 1, wn = wid & 1;
  const int lr = lane & 15, lg = lane >> 4;

  const unsigned short* Ab = A + (size_t)tm * 128 * Kdim;
  const unsigned short* Bb = Bw + (size_t)tn * 128 * Kdim;

  f32x4 acc[4][4] = {};

  const unsigned short* sa[4];
  const unsigned short* sb[4];
  unsigned short* da[4];
  unsigned short* db[4];
#pragma unroll
  for (int p = 0; p < 4; ++p) {
    int cl = p * 256 + tid;
    int ri = cl >> 3, c = cl & 7;
    int cg = c ^ (ri & 7);
    sa[p] = Ab + (size_t)ri * Kdim + (cg << 3);
    sb[p] = Bb + (size_t)ri * Kdim + (cg << 3);
    da[p] = lA + ri * 64 + (c << 3);
    db[p] = lB + ri * 64 + (c << 3);
  }

  const int nt = Kdim >> 6;

  for (int k = 0; k < nt; ++k) {
#pragma unroll
    for (int p = 0; p < 4; ++p) {
      gll16(sa[p], da[p]); sa[p] += 64;
      gll16(sb[p], db[p]); sb[p] += 64;
    }
    __syncthreads();

    bf16x8 af[4][2], bf[4][2];
#pragma unroll
    for (int t = 0; t < 4; ++t) {
      int ra = wm * 64 + t * 16 + lr;
      int rb = wn * 64 + t * 16 + lr;
      af[t][0] = *reinterpret_cast<const bf16x8*>(lA + ra * 64 + ((lg ^ (ra & 7)) << 3));
      af[t][1] = *reinterpret_cast<const bf16x8*>(lA + ra * 64 + (((4 + lg) ^ (ra & 7)) << 3));
      bf[t][0] = *reinterpret_cast<const bf16x8*>(lB + rb * 64 + ((lg ^ (rb & 7)) << 3));
      bf[t][1] = *reinterpret_cast<const bf16x8*>(lB + rb * 64 + (((4 + lg) ^ (rb & 7)) << 3));
    }
#pragma unroll
    for (int i = 0; i < 4; ++i)
#pragma unroll
      for (int j = 0; j < 4; ++j) {
        acc[i][j] = MFMA16(af[i][0], bf[j][0], acc[i][j]);
        acc[i][j] = MFMA16(af[i][1], bf[j][1], acc[i][j]);
      }
    __syncthreads();
  }

#pragma unroll
  for (int i = 0; i < 4; ++i) {
#pragma unroll
    for (int j = 0; j < 4; ++j) {
      int n = tn * 128 + wn * 64 + j * 16 + lr;
#pragma unroll
      for (int r = 0; r < 4; ++r) {
        int m = tm * 128 + wm * 64 + i * 16 + lg * 4 + r;
        outF[(size_t)m * 2048 + n] = acc[i][j][r];
      }
    }
  }
}

// ---------------- flash attention (round-9 proven version) ----------------
// Block bx handles q-tiles {31-bx, bx}: every block does exactly 33 K-iters.
// K/V double-buffered; counted vmcnt(8); raw s_barrier; hoisted stage ptrs;
// T13 defer-max; exp2-domain softmax. 256 threads, VGPR unconstrained
// (round-10 lesson: forcing occupancy via launch_bounds min-waves spilled).

__global__ __launch_bounds__(256)
void attn_fwd(const unsigned short* __restrict__ Qr,
              const unsigned short* __restrict__ Kr,
              const unsigned short* __restrict__ Vt,
              unsigned short* __restrict__ attnb) {
  __shared__ unsigned short Ks[2][64 * 128];
  __shared__ unsigned short Vs[2][128 * 64];
  __shared__ unsigned short Ps[64 * 64];
  const int bx = blockIdx.x, bh = blockIdx.y;
  const int tid = threadIdx.x;
  const int wid = tid >> 6, lane = tid & 63;
  const int lr = lane & 15, lg = lane >> 4;
  const unsigned short* Qb = Qr + (size_t)bh * SS * HDD;
  const unsigned short* Kb = Kr + (size_t)bh * SS * HDD;
  const unsigned short* Vb = Vt + (size_t)bh * HDD * SS;
  const int b = bh >> 4, h = bh & 15;
  const float SC2 = 0.12751763f;               // 1/sqrt(128) * log2(e)

  const unsigned short* ksrc0[4];
  const unsigned short* vsrc0[4];
  int dst8[4];
#pragma unroll
  for (int ch = 0; ch < 4; ++ch) {
    int c = tid + ch * 256;
    int kr = c >> 4, kc = c & 15;
    ksrc0[ch] = Kb + (size_t)kr * 128 + ((kc ^ (kr & 7)) << 3);
    int vr = c >> 3, vc = c & 7;
    vsrc0[ch] = Vb + (size_t)vr * SS + ((vc ^ (vr & 7)) << 3);
    dst8[ch] = c * 8;
  }
  const unsigned short* ksrc[4];
  const unsigned short* vsrc[4];

  auto stage = [&](int buf) {
#pragma unroll
    for (int ch = 0; ch < 4; ++ch) {
      gll16(ksrc[ch], Ks[buf] + dst8[ch]); ksrc[ch] += 64 * 128;
      gll16(vsrc[ch], Vs[buf] + dst8[ch]); vsrc[ch] += 64;
    }
  };

#pragma unroll 1
  for (int qi = 0; qi < 2; ++qi) {
    const int qt = qi ? bx : (31 - bx);

#pragma unroll
    for (int ch = 0; ch < 4; ++ch) { ksrc[ch] = ksrc0[ch]; vsrc[ch] = vsrc0[ch]; }

    bf16x8 qf[4];
#pragma unroll
    for (int kk = 0; kk < 4; ++kk)
      qf[kk] = *reinterpret_cast<const bf16x8*>(
          Qb + ((size_t)(qt * 64 + wid * 16 + lr)) * 128 + kk * 32 + lg * 8);

    f32x4 oacc[8] = {};
    float mrow[4], lsum[4];
#pragma unroll
    for (int r = 0; r < 4; ++r) { mrow[r] = -1e30f; lsum[r] = 0.f; }

    int cur = 0;
    stage(0);

#pragma unroll 1
    for (int kt = 0; kt <= qt; ++kt) {
      if (kt < qt) {
        stage(cur ^ 1);
        wvm<8>();
      } else {
        wvm<0>();
      }
      __builtin_amdgcn_s_barrier();
      __builtin_amdgcn_sched_barrier(0);

      float sv[4][4];
#pragma unroll
      for (int nt = 0; nt < 4; ++nt) {
        f32x4 sa = {};
#pragma unroll
        for (int kk = 0; kk < 4; ++kk) {
          int row = nt * 16 + lr;
          bf16x8 kf = *reinterpret_cast<const bf16x8*>(
              Ks[cur] + row * 128 + (((kk * 4 + lg) ^ (row & 7)) << 3));
          sa = __builtin_amdgcn_mfma_f32_16x16x32_bf16(qf[kk], kf, sa, 0, 0, 0);
        }
#pragma unroll
        for (int r = 0; r < 4; ++r) {
          float s = sa[r] * SC2;
          if (kt == qt && (nt * 16 + lr) > (wid * 16 + lg * 4 + r)) s -= 1.5e9f;
          sv[nt][r] = s;
        }
      }

      float tmax[4];
#pragma unroll
      for (int r = 0; r < 4; ++r)
        tmax[r] = fmaxf(fmaxf(sv[0][r], sv[1][r]), fmaxf(sv[2][r], sv[3][r]));
#pragma unroll
      for (int r = 0; r < 4; ++r) {
        tmax[r] = fmaxf(tmax[r], __shfl_xor(tmax[r], 1));
        tmax[r] = fmaxf(tmax[r], __shfl_xor(tmax[r], 2));
        tmax[r] = fmaxf(tmax[r], __shfl_xor(tmax[r], 4));
        tmax[r] = fmaxf(tmax[r], __shfl_xor(tmax[r], 8));
      }

      float need = fmaxf(fmaxf(tmax[0] - mrow[0], tmax[1] - mrow[1]),
                         fmaxf(tmax[2] - mrow[2], tmax[3] - mrow[3]));
      if (__any(need > 11.54f)) {
#pragma unroll
        for (int r = 0; r < 4; ++r) {
          float mn = fmaxf(mrow[r], tmax[r]);
          float fr = exp2f(mrow[r] - mn);
          mrow[r] = mn;
          lsum[r] *= fr;
#pragma unroll
          for (int ct = 0; ct < 8; ++ct) oacc[ct][r] *= fr;
        }
      }

      float tsum[4] = {0.f, 0.f, 0.f, 0.f};
#pragma unroll
      for (int nt = 0; nt < 4; ++nt) {
        int colc = nt * 2 + (lr >> 3);
#pragma unroll
        for (int r = 0; r < 4; ++r) {
          float p = exp2f(sv[nt][r] - mrow[r]);
          tsum[r] += p;
          int row = wid * 16 + lg * 4 + r;
          Ps[row * 64 + ((colc ^ (row & 7)) << 3) + (lr & 7)] = f2bf(p);
        }
      }
#pragma unroll
      for (int r = 0; r < 4; ++r) {
        tsum[r] += __shfl_xor(tsum[r], 1);
        tsum[r] += __shfl_xor(tsum[r], 2);
        tsum[r] += __shfl_xor(tsum[r], 4);
        tsum[r] += __shfl_xor(tsum[r], 8);
        lsum[r] += tsum[r];
      }

      bf16x8 pf[2];
#pragma unroll
      for (int ks = 0; ks < 2; ++ks) {
        int row = wid * 16 + lr;
        pf[ks] = *reinterpret_cast<const bf16x8*>(
            Ps + row * 64 + (((ks * 4 + lg) ^ (row & 7)) << 3));
      }
#pragma unroll
      for (int ct = 0; ct < 8; ++ct) {
#pragma unroll
        for (int ks = 0; ks < 2; ++ks) {
          int row = ct * 16 + lr;
          bf16x8 vf = *reinterpret_cast<const bf16x8*>(
              Vs[cur] + row * 64 + (((ks * 4 + lg) ^ (row & 7)) << 3));
          oacc[ct] = __builtin_amdgcn_mfma_f32_16x16x32_bf16(pf[ks], vf, oacc[ct], 0, 0, 0);
        }
      }
      __builtin_amdgcn_s_barrier();
      cur ^= 1;
    }

#pragma unroll
    for (int r = 0; r < 4; ++r) {
      float rl = 1.f / lsum[r];
      int qg = qt * 64 + wid * 16 + lg * 4 + r;
#pragma unroll
      for (int ct = 0; ct < 8; ++ct) {
        int d = ct * 16 + lr;
        attnb[((size_t)b * SS + qg) * HH + h * 128 + d] = f2bf(oacc[ct][r] * rl);
      }
    }
  }
}

// ---------------- launch ----------------

extern "C" void kernel_launch(void* const* d_in, const int* in_sizes, int n_in,
                              void* d_out, int out_size, void* d_ws, size_t ws_size,
                              hipStream_t stream) {
  const float* hs     = (const float*)d_in[0];
  const int*   pos    = (const int*)d_in[1];
  const float* qkv_w  = (const float*)d_in[3];
  const float* qkv_b  = (const float*)d_in[4];
  const float* o_w    = (const float*)d_in[5];
  float* out = (float*)d_out;
  char* ws = (char*)d_ws;

  unsigned short* hsb   = (unsigned short*)(ws);                  // 16 MB
  unsigned short* wqkvb = (unsigned short*)(ws + 16777216);       // 24 MB
  unsigned short* owb   = (unsigned short*)(ws + 41943040);       // 8 MB
  unsigned short* Qr    = (unsigned short*)(ws + 50331648);       // 16 MB
  unsigned short* Kr    = (unsigned short*)(ws + 67108864);       // 16 MB
  unsigned short* Vt    = (unsigned short*)(ws + 83886080);       // 16 MB
  unsigned short* attnb = (unsigned short*)(ws + 100663296);      // 16 MB
  float*          tab   = (float*)(ws + 117440512);               // 1 MB

  // fused converts + rope table: (6291456 + 131072) / 256 = 25088 blocks
  prep<<<25088, 256, 0, stream>>>(hs, qkv_w, o_w, hsb, wqkvb, owb, tab);

  // QKV + fused RoPE: grid 24x16 = 384 blocks.
  gemm_qkv<<<dim3(24, 16), 512, 0, stream>>>(hsb, wqkvb, qkv_b, pos, tab, Qr, Kr, Vt, 2048);
  // attention: QBLK=64, grid 16x32 = 512 blocks, 256 threads (round-9 proven).
  attn_fwd<<<dim3(16, 32), 256, 0, stream>>>(Qr, Kr, Vt, attnb);
  // O-proj: 128x128 m97-regime, grid 16x32 = 512 blocks.
  gemm97<0><<<dim3(16, 32), 256, 0, stream>>>(attnb, owb, out, 2048);
}

// Round 12
// 269.248 us; speedup vs baseline: 1.1134x; 1.0154x over previous
//
#include <hip/hip_runtime.h>
#include <hip/hip_bf16.h>

#define BB 2
#define SS 2048
#define HH 2048
#define NHH 16
#define HDD 128

using f32x4  = __attribute__((ext_vector_type(4))) float;
using bf16x8 = __attribute__((ext_vector_type(8))) short;

__device__ __forceinline__ unsigned short f2bf(float x) {
  unsigned int u = __float_as_uint(x);
  unsigned int r = (u + 0x7FFFu + ((u >> 16) & 1u)) >> 16;
  return (unsigned short)r;
}
__device__ __forceinline__ float bf2f(unsigned short u) {
  return __uint_as_float(((unsigned int)u) << 16);
}

__device__ __forceinline__ void gll16(const void* g, void* l) {
  __builtin_amdgcn_global_load_lds(
      (__attribute__((address_space(1))) void*)(g),
      (__attribute__((address_space(3))) void*)(l), 16, 0, 0);
}

#define MFMA16(a, b, c) __builtin_amdgcn_mfma_f32_16x16x32_bf16(a, b, c, 0, 0, 0)

template<int N> __device__ __forceinline__ void wlgkm() {
  static_assert(N == 0 || N == 4 || N == 8, "unsupported lgkmcnt");
  if constexpr (N == 0)      asm volatile("s_waitcnt lgkmcnt(0)" ::: "memory");
  else if constexpr (N == 4) asm volatile("s_waitcnt lgkmcnt(4)" ::: "memory");
  else if constexpr (N == 8) asm volatile("s_waitcnt lgkmcnt(8)" ::: "memory");
}
template<int N> __device__ __forceinline__ void wvm() {
  static_assert(N == 0 || N == 4 || N == 8, "unsupported vmcnt");
  if constexpr (N == 0)      asm volatile("s_waitcnt vmcnt(0)" ::: "memory");
  else if constexpr (N == 4) asm volatile("s_waitcnt vmcnt(4)" ::: "memory");
  else if constexpr (N == 8) asm volatile("s_waitcnt vmcnt(8)" ::: "memory");
}

// ---------------- fused prep: 3 bf16 converts + rope table (1 launch) ----------

__global__ void prep(const float* __restrict__ hs, const float* __restrict__ qkv_w,
                     const float* __restrict__ o_w, unsigned short* __restrict__ hsb,
                     unsigned short* __restrict__ wqkvb, unsigned short* __restrict__ owb,
                     float* __restrict__ tab) {
  int i = blockIdx.x * blockDim.x + threadIdx.x;
  if (i < 6291456) {                       // float4-unit converts
    const float* src; unsigned short* dst; int j;
    if (i < 2097152)      { src = hs;    dst = hsb;   j = i; }
    else if (i < 5242880) { src = qkv_w; dst = wqkvb; j = i - 2097152; }
    else                  { src = o_w;   dst = owb;   j = i - 5242880; }
    float4 v = reinterpret_cast<const float4*>(src)[j];
    ushort4 o;
    o.x = f2bf(v.x); o.y = f2bf(v.y); o.z = f2bf(v.z); o.w = f2bf(v.w);
    reinterpret_cast<ushort4*>(dst)[j] = o;
  } else {                                 // tab: [S][64][2] = cos,sin
    int j = i - 6291456;                   // 0..131071
    int s = j >> 6, jj = j & 63;
    float invf = expf(-logf(10000.f) * ((float)jj / 64.f));
    float a = (float)s * invf;
    tab[j * 2]     = cosf(a);
    tab[j * 2 + 1] = sinf(a);
  }
}

// ---------- QKV GEMM: round-3 pipeline + fused RoPE epilogue (117 us proven) ----

__global__ __launch_bounds__(512, 1)
void gemm_qkv(const unsigned short* __restrict__ A,
              const unsigned short* __restrict__ Bw,
              const float* __restrict__ bias,
              const int* __restrict__ pos,
              const float* __restrict__ tab,
              unsigned short* __restrict__ outQ,
              unsigned short* __restrict__ outK,
              unsigned short* __restrict__ outV,
              int Kdim) {
  __shared__ unsigned short lds_[4][256 * 64];   // lA = slots 0-1, lB = slots 2-3
  const int tid = threadIdx.x;
  const int tn = blockIdx.x, tm = blockIdx.y;
  const int wid = tid >> 6, lane = tid & 63;
  const int wm = wid >> 2, wn = wid & 3;      // 2 x 4 wave grid
  const int lr = lane & 15, lg = lane >> 4;

  const unsigned short* Ab = A + (size_t)tm * 256 * Kdim;
  const unsigned short* Bb = Bw + (size_t)tn * 256 * Kdim;

  f32x4 acc[8][4] = {};
  bf16x8 af[8][2], bfr[4][2];

  const int nt = Kdim >> 6;

  auto stageA = [&](int t, int h) {
    unsigned short* L = lds_[t & 1];
    const int k0 = t << 6;
#pragma unroll
    for (int p = 0; p < 2; ++p) {
      int cl = p * 512 + tid;
      int ri = cl >> 3, c = cl & 7;
      int row = (ri >> 6) * 128 + h * 64 + (ri & 63);
      int cg = c ^ (row & 7);
      gll16(Ab + (size_t)row * Kdim + k0 + (cg << 3), L + row * 64 + (c << 3));
    }
  };
  auto stageB = [&](int t, int h) {
    unsigned short* L = lds_[2 + (t & 1)];
    const int k0 = t << 6;
#pragma unroll
    for (int p = 0; p < 2; ++p) {
      int cl = p * 512 + tid;
      int ri = cl >> 3, c = cl & 7;
      int row = (ri >> 5 << 6) + (h << 5) + (ri & 31);
      int cg = c ^ (row & 7);
      gll16(Bb + (size_t)row * Kdim + k0 + (cg << 3), L + row * 64 + (c << 3));
    }
  };
  auto readAhalf = [&](int g, int h) {
    const unsigned short* la = lds_[g & 1];
#pragma unroll
    for (int mi = h * 4; mi < h * 4 + 4; ++mi) {
      int ra = wm * 128 + mi * 16 + lr;
      af[mi][0] = *reinterpret_cast<const bf16x8*>(la + ra * 64 + ((lg ^ (ra & 7)) << 3));
      af[mi][1] = *reinterpret_cast<const bf16x8*>(la + ra * 64 + (((4 + lg) ^ (ra & 7)) << 3));
    }
  };
  auto readBhalf = [&](int g, int h) {
    const unsigned short* lb = lds_[2 + (g & 1)];
#pragma unroll
    for (int ni = h * 2; ni < h * 2 + 2; ++ni) {
      int rb = wn * 64 + ni * 16 + lr;
      bfr[ni][0] = *reinterpret_cast<const bf16x8*>(lb + rb * 64 + ((lg ^ (rb & 7)) << 3));
      bfr[ni][1] = *reinterpret_cast<const bf16x8*>(lb + rb * 64 + (((4 + lg) ^ (rb & 7)) << 3));
    }
  };
  auto quad = [&](int ah, int bh) {
    __builtin_amdgcn_s_setprio(1);
#pragma unroll
    for (int mi = ah * 4; mi < ah * 4 + 4; ++mi)
#pragma unroll
      for (int ni = bh * 2; ni < bh * 2 + 2; ++ni) {
        acc[mi][ni] = MFMA16(af[mi][0], bfr[ni][0], acc[mi][ni]);
        acc[mi][ni] = MFMA16(af[mi][1], bfr[ni][1], acc[mi][ni]);
      }
    __builtin_amdgcn_s_setprio(0);
  };

  // ---- prologue
  stageA(0, 0); stageA(0, 1); stageB(0, 0); stageB(0, 1);
  stageA(1, 0); stageA(1, 1); stageB(1, 0); stageB(1, 1);
  wvm<8>();
  __builtin_amdgcn_s_barrier();
  __builtin_amdgcn_sched_barrier(0);
  readAhalf(0, 0);
  readBhalf(0, 0);

  for (int g = 0; g < nt; ++g) {
    readBhalf(g, 1);
    wlgkm<4>();
    __builtin_amdgcn_sched_barrier(0);
    quad(0, 0);

    readAhalf(g, 1);
    wlgkm<8>();
    __builtin_amdgcn_sched_barrier(0);
    quad(0, 1);

    asm volatile("s_waitcnt vmcnt(0) lgkmcnt(0)" ::: "memory");
    __builtin_amdgcn_s_barrier();
    __builtin_amdgcn_sched_barrier(0);
    if (g + 1 < nt) readAhalf(g + 1, 0);
    if (g + 2 < nt) { stageA(g + 2, 0); stageA(g + 2, 1); }
    quad(1, 0);

    if (g + 1 < nt) readBhalf(g + 1, 0);
    if (g + 2 < nt) { stageB(g + 2, 0); stageB(g + 2, 1); }
    quad(1, 1);
  }

  // ---------------- epilogue ----------------
  if (tn < 16) {
    // Q/K: stage 256x256 bf16 to LDS (row-XOR swizzle), fused rope, bf16x8 stores.
    unsigned short* Ls = &lds_[0][0];
    __syncthreads();
#pragma unroll
    for (int mi = 0; mi < 8; ++mi) {
#pragma unroll
      for (int ni = 0; ni < 4; ++ni) {
        int n_l = wn * 64 + ni * 16 + lr;
        float bv = bias[tn * 256 + n_l];
#pragma unroll
        for (int r = 0; r < 4; ++r) {
          int m_l = wm * 128 + mi * 16 + lg * 4 + r;
          Ls[m_l * 256 + (n_l ^ ((m_l & 7) << 3))] = f2bf(acc[mi][ni][r] + bv);
        }
      }
    }
    __syncthreads();

    unsigned short* outX = (tn < 8) ? outQ : outK;
    const int jb = (tid & 7) * 8;
    const int r0 = (tid >> 3) * 4;
#pragma unroll
    for (int rr = 0; rr < 4; ++rr) {
      int row = r0 + rr;
      int m = tm * 256 + row;
      int b = m >> 11, s = m & 2047;
      int p = pos[b * 2048 + s];
      float cs[8], sn[8];
#pragma unroll
      for (int j = 0; j < 8; ++j) {
        float2 t2 = *reinterpret_cast<const float2*>(&tab[((size_t)p * 64 + jb + j) * 2]);
        cs[j] = t2.x; sn[j] = t2.y;
      }
      int swz = (row & 7) << 3;
#pragma unroll
      for (int hb = 0; hb < 2; ++hb) {
        bf16x8 x1 = *reinterpret_cast<const bf16x8*>(&Ls[row * 256 + (hb * 128 + (jb ^ swz))]);
        bf16x8 x2 = *reinterpret_cast<const bf16x8*>(&Ls[row * 256 + (hb * 128 + 64 + (jb ^ swz))]);
        bf16x8 y1, y2;
#pragma unroll
        for (int j = 0; j < 8; ++j) {
          float a1 = bf2f((unsigned short)x1[j]);
          float a2 = bf2f((unsigned short)x2[j]);
          y1[j] = (short)f2bf(a1 * cs[j] - a2 * sn[j]);
          y2[j] = (short)f2bf(a2 * cs[j] + a1 * sn[j]);
        }
        int n0 = tn * 256 + hb * 128;
        int h = (n0 >> 7) & 15;
        unsigned short* dst = outX + (((size_t)(b * 16 + h)) * 2048 + s) * 128;
        *reinterpret_cast<bf16x8*>(&dst[jb]) = y1;
        *reinterpret_cast<bf16x8*>(&dst[64 + jb]) = y2;
      }
    }
  } else {
    // V: transposed scalar stores (unchanged).
#pragma unroll
    for (int mi = 0; mi < 8; ++mi) {
#pragma unroll
      for (int ni = 0; ni < 4; ++ni) {
        int n = tn * 256 + wn * 64 + ni * 16 + lr;
        float bv = bias[n];
        int h = (n >> 7) & 15;
        int d = n & 127;
#pragma unroll
        for (int r = 0; r < 4; ++r) {
          int m = tm * 256 + wm * 128 + mi * 16 + lg * 4 + r;
          int b = m >> 11;
          int s = m & 2047;
          outV[(((size_t)(b * 16 + h)) * 128 + d) * 2048 + s] = f2bf(acc[mi][ni][r] + bv);
        }
      }
    }
  }
}

// ---------- 128x128 m97-regime GEMM (O-projection) ----------

template<int MODE>
__global__ __launch_bounds__(256)
void gemm97(const unsigned short* __restrict__ A,
            const unsigned short* __restrict__ Bw,
            float* __restrict__ outF,
            int Kdim) {
  __shared__ unsigned short lA[128 * 64];
  __shared__ unsigned short lB[128 * 64];
  const int tid = threadIdx.x;
  const int tn = blockIdx.x, tm = blockIdx.y;
  const int wid = tid >> 6, lane = tid & 63;
  const int wm = wid >> 1, wn = wid & 1;
  const int lr = lane & 15, lg = lane >> 4;

  const unsigned short* Ab = A + (size_t)tm * 128 * Kdim;
  const unsigned short* Bb = Bw + (size_t)tn * 128 * Kdim;

  f32x4 acc[4][4] = {};

  const unsigned short* sa[4];
  const unsigned short* sb[4];
  unsigned short* da[4];
  unsigned short* db[4];
#pragma unroll
  for (int p = 0; p < 4; ++p) {
    int cl = p * 256 + tid;
    int ri = cl >> 3, c = cl & 7;
    int cg = c ^ (ri & 7);
    sa[p] = Ab + (size_t)ri * Kdim + (cg << 3);
    sb[p] = Bb + (size_t)ri * Kdim + (cg << 3);
    da[p] = lA + ri * 64 + (c << 3);
    db[p] = lB + ri * 64 + (c << 3);
  }

  const int nt = Kdim >> 6;

  for (int k = 0; k < nt; ++k) {
#pragma unroll
    for (int p = 0; p < 4; ++p) {
      gll16(sa[p], da[p]); sa[p] += 64;
      gll16(sb[p], db[p]); sb[p] += 64;
    }
    __syncthreads();

    bf16x8 af[4][2], bf[4][2];
#pragma unroll
    for (int t = 0; t < 4; ++t) {
      int ra = wm * 64 + t * 16 + lr;
      int rb = wn * 64 + t * 16 + lr;
      af[t][0] = *reinterpret_cast<const bf16x8*>(lA + ra * 64 + ((lg ^ (ra & 7)) << 3));
      af[t][1] = *reinterpret_cast<const bf16x8*>(lA + ra * 64 + (((4 + lg) ^ (ra & 7)) << 3));
      bf[t][0] = *reinterpret_cast<const bf16x8*>(lB + rb * 64 + ((lg ^ (rb & 7)) << 3));
      bf[t][1] = *reinterpret_cast<const bf16x8*>(lB + rb * 64 + (((4 + lg) ^ (rb & 7)) << 3));
    }
#pragma unroll
    for (int i = 0; i < 4; ++i)
#pragma unroll
      for (int j = 0; j < 4; ++j) {
        acc[i][j] = MFMA16(af[i][0], bf[j][0], acc[i][j]);
        acc[i][j] = MFMA16(af[i][1], bf[j][1], acc[i][j]);
      }
    __syncthreads();
  }

#pragma unroll
  for (int i = 0; i < 4; ++i) {
#pragma unroll
    for (int j = 0; j < 4; ++j) {
      int n = tn * 128 + wn * 64 + j * 16 + lr;
#pragma unroll
      for (int r = 0; r < 4; ++r) {
        int m = tm * 128 + wm * 64 + i * 16 + lg * 4 + r;
        outF[(size_t)m * 2048 + n] = acc[i][j][r];
      }
    }
  }
}

// ---------------- flash attention: QBLK=128, 8 waves, work-balanced ----------------
// Block bx handles q-tiles {15-bx, bx} (128 rows each): exactly 34 kv-iters.
// K/V double-buffered; stage(kt+1) before compute(kt); counted vmcnt(4)
// (4 loads/thread/stage at 512 thr); raw s_barrier; T13 defer-max; exp2 domain.
// Correctness proven in round 10. Round-10's regression was SOLELY the
// __launch_bounds__(512,4) VGPR-64 cap (spilled ~120-reg live set). Plain
// (512) bounds: allocator free; either 2 blocks/CU (VGPR<=128) or 1 (same
// TLP as r9) — staging per FLOP halved in both cases.

__global__ __launch_bounds__(512)
void attn_fwd(const unsigned short* __restrict__ Qr,
              const unsigned short* __restrict__ Kr,
              const unsigned short* __restrict__ Vt,
              unsigned short* __restrict__ attnb) {
  __shared__ unsigned short Ks[2][64 * 128];   // 32 KB
  __shared__ unsigned short Vs[2][128 * 64];   // 32 KB
  __shared__ unsigned short Ps[128 * 64];      // 16 KB
  const int bx = blockIdx.x, bh = blockIdx.y;
  const int tid = threadIdx.x;
  const int wid = tid >> 6, lane = tid & 63;   // wid 0..7 -> q-rows wid*16..
  const int lr = lane & 15, lg = lane >> 4;
  const unsigned short* Qb = Qr + (size_t)bh * SS * HDD;
  const unsigned short* Kb = Kr + (size_t)bh * SS * HDD;
  const unsigned short* Vb = Vt + (size_t)bh * HDD * SS;
  const int b = bh >> 4, h = bh & 15;
  const float SC2 = 0.12751763f;               // 1/sqrt(128) * log2(e)

#pragma unroll 1
  for (int qi = 0; qi < 2; ++qi) {
    const int qt = qi ? bx : (15 - bx);        // q-tile of 128 rows
    const int nkt = 2 * qt + 2;                // kv-tiles of 64

    const unsigned short* ksrc[2];
    const unsigned short* vsrc[2];
    int dst8[2];
#pragma unroll
    for (int ch = 0; ch < 2; ++ch) {
      int c = tid + ch * 512;                  // 0..1023 chunks
      int kr = c >> 4, kc = c & 15;
      ksrc[ch] = Kb + (size_t)kr * 128 + ((kc ^ (kr & 7)) << 3);
      int vr = c >> 3, vc = c & 7;
      vsrc[ch] = Vb + (size_t)vr * SS + ((vc ^ (vr & 7)) << 3);
      dst8[ch] = c * 8;
    }

    bf16x8 qf[4];
#pragma unroll
    for (int kk = 0; kk < 4; ++kk)
      qf[kk] = *reinterpret_cast<const bf16x8*>(
          Qb + ((size_t)(qt * 128 + wid * 16 + lr)) * 128 + kk * 32 + lg * 8);

    f32x4 oacc[8] = {};
    float mrow[4], lsum[4];
#pragma unroll
    for (int r = 0; r < 4; ++r) { mrow[r] = -1e30f; lsum[r] = 0.f; }

    int cur = 0;
    // stage kv-tile 0 into buf 0
#pragma unroll
    for (int ch = 0; ch < 2; ++ch) {
      gll16(ksrc[ch], Ks[0] + dst8[ch]); ksrc[ch] += 64 * 128;
      gll16(vsrc[ch], Vs[0] + dst8[ch]); vsrc[ch] += 64;
    }

#pragma unroll 1
    for (int kt = 0; kt < nkt; ++kt) {
      if (kt + 1 < nkt) {
#pragma unroll
        for (int ch = 0; ch < 2; ++ch) {
          gll16(ksrc[ch], Ks[cur ^ 1] + dst8[ch]); ksrc[ch] += 64 * 128;
          gll16(vsrc[ch], Vs[cur ^ 1] + dst8[ch]); vsrc[ch] += 64;
        }
        wvm<4>();                              // retire stage(kt)
      } else {
        wvm<0>();
      }
      __builtin_amdgcn_s_barrier();
      __builtin_amdgcn_sched_barrier(0);

      float sv[4][4];
#pragma unroll
      for (int nt = 0; nt < 4; ++nt) {
        f32x4 sa = {};
#pragma unroll
        for (int kk = 0; kk < 4; ++kk) {
          int row = nt * 16 + lr;
          bf16x8 kf = *reinterpret_cast<const bf16x8*>(
              Ks[cur] + row * 128 + (((kk * 4 + lg) ^ (row & 7)) << 3));
          sa = __builtin_amdgcn_mfma_f32_16x16x32_bf16(qf[kk], kf, sa, 0, 0, 0);
        }
#pragma unroll
        for (int r = 0; r < 4; ++r) {
          float s = sa[r] * SC2;
          // mask only possible when kt>>1 == qt; kv offset within = (kt&1)*64
          if ((kt >> 1) == qt &&
              ((kt & 1) << 6) + nt * 16 + lr > wid * 16 + lg * 4 + r) s -= 1.5e9f;
          sv[nt][r] = s;
        }
      }

      float tmax[4];
#pragma unroll
      for (int r = 0; r < 4; ++r)
        tmax[r] = fmaxf(fmaxf(sv[0][r], sv[1][r]), fmaxf(sv[2][r], sv[3][r]));
#pragma unroll
      for (int r = 0; r < 4; ++r) {
        tmax[r] = fmaxf(tmax[r], __shfl_xor(tmax[r], 1));
        tmax[r] = fmaxf(tmax[r], __shfl_xor(tmax[r], 2));
        tmax[r] = fmaxf(tmax[r], __shfl_xor(tmax[r], 4));
        tmax[r] = fmaxf(tmax[r], __shfl_xor(tmax[r], 8));
      }

      float need = fmaxf(fmaxf(tmax[0] - mrow[0], tmax[1] - mrow[1]),
                         fmaxf(tmax[2] - mrow[2], tmax[3] - mrow[3]));
      if (__any(need > 11.54f)) {
#pragma unroll
        for (int r = 0; r < 4; ++r) {
          float mn = fmaxf(mrow[r], tmax[r]);
          float fr = exp2f(mrow[r] - mn);
          mrow[r] = mn;
          lsum[r] *= fr;
#pragma unroll
          for (int ct = 0; ct < 8; ++ct) oacc[ct][r] *= fr;
        }
      }

      float tsum[4] = {0.f, 0.f, 0.f, 0.f};
#pragma unroll
      for (int nt = 0; nt < 4; ++nt) {
        int colc = nt * 2 + (lr >> 3);
#pragma unroll
        for (int r = 0; r < 4; ++r) {
          float p = exp2f(sv[nt][r] - mrow[r]);
          tsum[r] += p;
          int row = wid * 16 + lg * 4 + r;    // 0..127
          Ps[row * 64 + ((colc ^ (row & 7)) << 3) + (lr & 7)] = f2bf(p);
        }
      }
#pragma unroll
      for (int r = 0; r < 4; ++r) {
        tsum[r] += __shfl_xor(tsum[r], 1);
        tsum[r] += __shfl_xor(tsum[r], 2);
        tsum[r] += __shfl_xor(tsum[r], 4);
        tsum[r] += __shfl_xor(tsum[r], 8);
        lsum[r] += tsum[r];
      }

      bf16x8 pf[2];
#pragma unroll
      for (int ks = 0; ks < 2; ++ks) {
        int row = wid * 16 + lr;
        pf[ks] = *reinterpret_cast<const bf16x8*>(
            Ps + row * 64 + (((ks * 4 + lg) ^ (row & 7)) << 3));
      }
#pragma unroll
      for (int ct = 0; ct < 8; ++ct) {
#pragma unroll
        for (int ks = 0; ks < 2; ++ks) {
          int row = ct * 16 + lr;
          bf16x8 vf = *reinterpret_cast<const bf16x8*>(
              Vs[cur] + row * 64 + (((ks * 4 + lg) ^ (row & 7)) << 3));
          oacc[ct] = __builtin_amdgcn_mfma_f32_16x16x32_bf16(pf[ks], vf, oacc[ct], 0, 0, 0);
        }
      }
      __builtin_amdgcn_s_barrier();            // readers of buf 'cur' done
      cur ^= 1;
    }

#pragma unroll
    for (int r = 0; r < 4; ++r) {
      float rl = 1.f / lsum[r];
      int qg = qt * 128 + wid * 16 + lg * 4 + r;
#pragma unroll
      for (int ct = 0; ct < 8; ++ct) {
        int d = ct * 16 + lr;
        attnb[((size_t)b * SS + qg) * HH + h * 128 + d] = f2bf(oacc[ct][r] * rl);
      }
    }
  }
}

// ---------------- launch ----------------

extern "C" void kernel_launch(void* const* d_in, const int* in_sizes, int n_in,
                              void* d_out, int out_size, void* d_ws, size_t ws_size,
                              hipStream_t stream) {
  const float* hs     = (const float*)d_in[0];
  const int*   pos    = (const int*)d_in[1];
  const float* qkv_w  = (const float*)d_in[3];
  const float* qkv_b  = (const float*)d_in[4];
  const float* o_w    = (const float*)d_in[5];
  float* out = (float*)d_out;
  char* ws = (char*)d_ws;

  unsigned short* hsb   = (unsigned short*)(ws);                  // 16 MB
  unsigned short* wqkvb = (unsigned short*)(ws + 16777216);       // 24 MB
  unsigned short* owb   = (unsigned short*)(ws + 41943040);       // 8 MB
  unsigned short* Qr    = (unsigned short*)(ws + 50331648);       // 16 MB
  unsigned short* Kr    = (unsigned short*)(ws + 67108864);       // 16 MB
  unsigned short* Vt    = (unsigned short*)(ws + 83886080);       // 16 MB
  unsigned short* attnb = (unsigned short*)(ws + 100663296);      // 16 MB
  float*          tab   = (float*)(ws + 117440512);               // 1 MB

  // fused converts + rope table: (6291456 + 131072) / 256 = 25088 blocks
  prep<<<25088, 256, 0, stream>>>(hs, qkv_w, o_w, hsb, wqkvb, owb, tab);

  // QKV + fused RoPE: grid 24x16 = 384 blocks.
  gemm_qkv<<<dim3(24, 16), 512, 0, stream>>>(hsb, wqkvb, qkv_b, pos, tab, Qr, Kr, Vt, 2048);
  // attention: QBLK=128, grid 8x32 = 256 blocks, 512 threads (VGPR unconstrained).
  attn_fwd<<<dim3(8, 32), 512, 0, stream>>>(Qr, Kr, Vt, attnb);
  // O-proj: 128x128 m97-regime, grid 16x32 = 512 blocks.
  gemm97<0><<<dim3(16, 32), 256, 0, stream>>>(attnb, owb, out, 2048);
}